// Round 1
// baseline (307.990 us; speedup 1.0000x reference)
//
#include <hip/hip_runtime.h>
#include <hip/hip_bf16.h>

typedef __attribute__((ext_vector_type(8))) __bf16 bf16x8;
typedef __attribute__((ext_vector_type(4))) float f32x4;
typedef __attribute__((ext_vector_type(4))) unsigned short u16x4;
typedef unsigned short u16;

#define AS3(p) ((__attribute__((address_space(3))) void*)(p))
#define AS1(p) ((const __attribute__((address_space(1))) void*)(p))

__device__ __forceinline__ u16 f2b(float f) {
    __hip_bfloat16 h = __float2bfloat16(f);
    return __builtin_bit_cast(u16, h);
}

// ---------------------------------------------------------------------------
// Weight transpose: W [K][N] fp32 -> WT [N][K] bf16 (tiled, padded LDS)
// ---------------------------------------------------------------------------
__global__ __launch_bounds__(256) void transpose_w(
    const float* __restrict__ W, u16* __restrict__ WT, int K, int N)
{
    __shared__ u16 tile[32][33];
    const int tx = threadIdx.x & 31, ty = threadIdx.x >> 5;
    const int n0 = blockIdx.x * 32, k0 = blockIdx.y * 32;
    #pragma unroll
    for (int p = 0; p < 4; ++p)
        tile[ty + p * 8][tx] = f2b(W[(size_t)(k0 + ty + p * 8) * N + n0 + tx]);
    __syncthreads();
    #pragma unroll
    for (int p = 0; p < 4; ++p)
        WT[(size_t)(n0 + ty + p * 8) * K + k0 + tx] = tile[tx][ty + p * 8];
}

// ---------------------------------------------------------------------------
// LayerNorm: x fp32 [rows][1024] -> y bf16, one block per row
// ---------------------------------------------------------------------------
__global__ __launch_bounds__(256) void ln_bf16(
    const float* __restrict__ xin, const float* __restrict__ gam,
    const float* __restrict__ bet, u16* __restrict__ yout)
{
    __shared__ float red[8];
    const int row = blockIdx.x, tid = threadIdx.x;
    float4 v = ((const float4*)(xin + (size_t)row * 1024))[tid];
    float s = v.x + v.y + v.z + v.w;
    #pragma unroll
    for (int o = 32; o > 0; o >>= 1) s += __shfl_xor(s, o, 64);
    if ((tid & 63) == 0) red[tid >> 6] = s;
    __syncthreads();
    const float mu = (red[0] + red[1] + red[2] + red[3]) * (1.f / 1024.f);
    const float dx = v.x - mu, dy = v.y - mu, dz = v.z - mu, dw = v.w - mu;
    float sq = dx * dx + dy * dy + dz * dz + dw * dw;
    #pragma unroll
    for (int o = 32; o > 0; o >>= 1) sq += __shfl_xor(sq, o, 64);
    if ((tid & 63) == 0) red[4 + (tid >> 6)] = sq;
    __syncthreads();
    const float var = (red[4] + red[5] + red[6] + red[7]) * (1.f / 1024.f);
    const float inv = rsqrtf(var + 1e-5f);
    const float4 G = ((const float4*)gam)[tid];
    const float4 Bt = ((const float4*)bet)[tid];
    u16x4 o;
    o[0] = f2b(dx * inv * G.x + Bt.x);
    o[1] = f2b(dy * inv * G.y + Bt.y);
    o[2] = f2b(dz * inv * G.z + Bt.z);
    o[3] = f2b(dw * inv * G.w + Bt.w);
    ((u16x4*)(yout + (size_t)row * 1024))[tid] = o;
}

// ---------------------------------------------------------------------------
// GEMM: C[M][N] = A[M][K](bf16) @ BT[N][K]^T(bf16) + epilogue
// m97 structure: 128x128 tile, BK=64, 4 waves (2x2), global_load_lds w=16,
// XOR-swizzled LDS via pre-swizzled global source (G21), 2 barriers/K-step.
// MODE 0: bias(3-way QKV select), out bf16
// MODE 1: bias + residual(fp32), out fp32
// MODE 2: bias + exact GELU, out bf16
// ---------------------------------------------------------------------------
template <int MODE>
__global__ __launch_bounds__(256) void gemm_bf16(
    const u16* __restrict__ A, const u16* __restrict__ BT,
    const float* __restrict__ b0, const float* __restrict__ b1,
    const float* __restrict__ b2, const float* __restrict__ resid,
    void* __restrict__ outp, int M, int N, int K)
{
    __shared__ u16 Asm[128 * 64];
    __shared__ u16 Bsm[128 * 64];
    const int tid = threadIdx.x;
    const int lane = tid & 63, wid = tid >> 6;
    const int bn0 = blockIdx.x * 128, bm0 = blockIdx.y * 128;
    const int wm = wid >> 1, wn = wid & 1;
    const int g = lane >> 4, l16 = lane & 15;
    const int srow = lane >> 3;              // 0..7 within 8-row chunk
    const int sslot = (lane & 7) ^ srow;     // inverse-swizzled k-slot (16B units)

    f32x4 acc[4][4] = {};

    const u16* aBase = A + (size_t)bm0 * K + sslot * 8;
    const u16* bBase = BT + (size_t)bn0 * K + sslot * 8;

    for (int kt = 0; kt < K; kt += 64) {
        __syncthreads();
        #pragma unroll
        for (int j = 0; j < 4; ++j) {
            const int inst = wid * 4 + j;          // 16 insts per tile, 4/wave
            const int row = inst * 8 + srow;       // 0..127
            __builtin_amdgcn_global_load_lds(AS1(aBase + (size_t)row * K + kt),
                                             AS3(Asm + inst * 512), 16, 0, 0);
            __builtin_amdgcn_global_load_lds(AS1(bBase + (size_t)row * K + kt),
                                             AS3(Bsm + inst * 512), 16, 0, 0);
        }
        __syncthreads();
        #pragma unroll
        for (int ks = 0; ks < 2; ++ks) {
            bf16x8 af[4], bfr[4];
            #pragma unroll
            for (int mi = 0; mi < 4; ++mi) {
                const int r = wm * 64 + mi * 16 + l16;
                const int slot = (g + 4 * ks) ^ (r & 7);   // swizzled read
                af[mi] = *(const bf16x8*)(Asm + r * 64 + slot * 8);
            }
            #pragma unroll
            for (int ni = 0; ni < 4; ++ni) {
                const int r = wn * 64 + ni * 16 + l16;
                const int slot = (g + 4 * ks) ^ (r & 7);
                bfr[ni] = *(const bf16x8*)(Bsm + r * 64 + slot * 8);
            }
            #pragma unroll
            for (int mi = 0; mi < 4; ++mi)
                #pragma unroll
                for (int ni = 0; ni < 4; ++ni)
                    acc[mi][ni] = __builtin_amdgcn_mfma_f32_16x16x32_bf16(
                        af[mi], bfr[ni], acc[mi][ni], 0, 0, 0);
        }
    }

    #pragma unroll
    for (int mi = 0; mi < 4; ++mi) {
        #pragma unroll
        for (int ni = 0; ni < 4; ++ni) {
            #pragma unroll
            for (int j = 0; j < 4; ++j) {
                const int m = bm0 + wm * 64 + mi * 16 + g * 4 + j;  // C/D: row=4g+j
                const int n = bn0 + wn * 64 + ni * 16 + l16;        // C/D: col=l16
                float v = acc[mi][ni][j];
                if constexpr (MODE == 0) {
                    const float bias = (n < 1024) ? b0[n]
                                      : (n < 2048) ? b1[n - 1024] : b2[n - 2048];
                    ((u16*)outp)[(size_t)m * N + n] = f2b(v + bias);
                } else if constexpr (MODE == 1) {
                    ((float*)outp)[(size_t)m * N + n] =
                        v + b0[n] + resid[(size_t)m * N + n];
                } else {
                    v += b0[n];
                    v = 0.5f * v * (1.0f + erff(v * 0.70710678118654752f));
                    ((u16*)outp)[(size_t)m * N + n] = f2b(v);
                }
            }
        }
    }
}

// ---------------------------------------------------------------------------
// Flash attention (causal): qkv bf16 [4096][3072] (q|k|v per row, head-major)
// Block = (q-tile of 64) x (b,h). 4 waves x 16 q-rows. KV tiles of 64 in LDS.
// Online softmax fully wave-parallel (shfl_xor within 16-lane groups).
// ---------------------------------------------------------------------------
__global__ __launch_bounds__(256) void attn_fwd(
    const u16* __restrict__ qkv, u16* __restrict__ outp)
{
    __shared__ u16 Ksm[64 * 72];        // K tile [kv][d], +8 pad
    __shared__ u16 Vsm[64 * 72];        // V^T tile [d][kv], +8 pad
    __shared__ u16 Psm[4][16 * 72];     // per-wave P [16 q][64 kv], +8 pad
    const int tid = threadIdx.x, lane = tid & 63, w = tid >> 6;
    const int qt = blockIdx.x, bh = blockIdx.y;
    const int b = bh >> 4, h = bh & 15;
    const int q0 = qt * 64;
    const int g = lane >> 4, l16 = lane & 15;

    bf16x8 qf0, qf1;   // Q fragment hoisted: row=l16, k(d)=8g(+32)
    {
        const u16* qp = qkv + (size_t)(b * 1024 + q0 + w * 16 + l16) * 3072
                        + h * 64 + g * 8;
        qf0 = *(const bf16x8*)qp;
        qf1 = *(const bf16x8*)(qp + 32);
    }
    float m_run[4] = {-1e30f, -1e30f, -1e30f, -1e30f};
    float l_run[4] = {0.f, 0.f, 0.f, 0.f};
    f32x4 oacc[4] = {};

    for (int kvt = 0; kvt <= qt; ++kvt) {
        const int kv0 = kvt * 64;
        __syncthreads();
        // stage K [kv][d] and V^T [d][kv]
        #pragma unroll
        for (int c = tid; c < 1024; c += 256) {
            const int kv = c >> 4, d4 = (c & 15) * 4;
            const u16* kp = qkv + (size_t)(b * 1024 + kv0 + kv) * 3072
                            + 1024 + h * 64 + d4;
            *(u16x4*)(Ksm + kv * 72 + d4) = *(const u16x4*)kp;
            const u16x4 vv = *(const u16x4*)(kp + 1024);
            Vsm[(d4 + 0) * 72 + kv] = vv[0];
            Vsm[(d4 + 1) * 72 + kv] = vv[1];
            Vsm[(d4 + 2) * 72 + kv] = vv[2];
            Vsm[(d4 + 3) * 72 + kv] = vv[3];
        }
        __syncthreads();

        // S = Q K^T  (4 kv-column tiles of 16)
        f32x4 s[4];
        #pragma unroll
        for (int t = 0; t < 4; ++t) {
            const bf16x8 kf0 = *(const bf16x8*)(Ksm + (t * 16 + l16) * 72 + g * 8);
            const bf16x8 kf1 = *(const bf16x8*)(Ksm + (t * 16 + l16) * 72 + 32 + g * 8);
            f32x4 z = {};
            z = __builtin_amdgcn_mfma_f32_16x16x32_bf16(qf0, kf0, z, 0, 0, 0);
            z = __builtin_amdgcn_mfma_f32_16x16x32_bf16(qf1, kf1, z, 0, 0, 0);
            s[t] = z;
        }
        // scale + causal mask + row max
        float mx[4] = {-1e30f, -1e30f, -1e30f, -1e30f};
        #pragma unroll
        for (int t = 0; t < 4; ++t)
            #pragma unroll
            for (int j = 0; j < 4; ++j) {
                const int qrow = q0 + w * 16 + g * 4 + j;
                const int kvc = kv0 + t * 16 + l16;
                float v = s[t][j] * 0.125f;
                if (kvc > qrow) v = -1e30f;
                s[t][j] = v;
                mx[j] = fmaxf(mx[j], v);
            }
        #pragma unroll
        for (int o = 1; o < 16; o <<= 1)
            #pragma unroll
            for (int j = 0; j < 4; ++j)
                mx[j] = fmaxf(mx[j], __shfl_xor(mx[j], o, 16));
        float alpha[4], rs[4];
        #pragma unroll
        for (int j = 0; j < 4; ++j) {
            const float mn = fmaxf(m_run[j], mx[j]);
            alpha[j] = __expf(m_run[j] - mn);
            m_run[j] = mn;
            rs[j] = 0.f;
        }
        #pragma unroll
        for (int t = 0; t < 4; ++t)
            #pragma unroll
            for (int j = 0; j < 4; ++j) {
                const float p = __expf(s[t][j] - m_run[j]);
                s[t][j] = p;
                rs[j] += p;
            }
        #pragma unroll
        for (int o = 1; o < 16; o <<= 1)
            #pragma unroll
            for (int j = 0; j < 4; ++j)
                rs[j] += __shfl_xor(rs[j], o, 16);
        #pragma unroll
        for (int j = 0; j < 4; ++j)
            l_run[j] = l_run[j] * alpha[j] + rs[j];
        #pragma unroll
        for (int dt = 0; dt < 4; ++dt)
            #pragma unroll
            for (int j = 0; j < 4; ++j)
                oacc[dt][j] *= alpha[j];
        // P -> LDS (C-layout) -> A-fragment layout
        #pragma unroll
        for (int t = 0; t < 4; ++t)
            #pragma unroll
            for (int j = 0; j < 4; ++j)
                Psm[w][(g * 4 + j) * 72 + t * 16 + l16] = f2b(s[t][j]);
        const bf16x8 pf0 = *(const bf16x8*)(&Psm[w][l16 * 72 + g * 8]);
        const bf16x8 pf1 = *(const bf16x8*)(&Psm[w][l16 * 72 + 32 + g * 8]);
        // O += P V
        #pragma unroll
        for (int dt = 0; dt < 4; ++dt) {
            const bf16x8 vf0 = *(const bf16x8*)(Vsm + (dt * 16 + l16) * 72 + g * 8);
            const bf16x8 vf1 = *(const bf16x8*)(Vsm + (dt * 16 + l16) * 72 + 32 + g * 8);
            oacc[dt] = __builtin_amdgcn_mfma_f32_16x16x32_bf16(pf0, vf0, oacc[dt], 0, 0, 0);
            oacc[dt] = __builtin_amdgcn_mfma_f32_16x16x32_bf16(pf1, vf1, oacc[dt], 0, 0, 0);
        }
    }
    #pragma unroll
    for (int dt = 0; dt < 4; ++dt)
        #pragma unroll
        for (int j = 0; j < 4; ++j) {
            const int m = b * 1024 + q0 + w * 16 + g * 4 + j;
            const int col = h * 64 + dt * 16 + l16;
            outp[(size_t)m * 1024 + col] = f2b(oacc[dt][j] / l_run[j]);
        }
}

// ---------------------------------------------------------------------------
extern "C" void kernel_launch(void* const* d_in, const int* in_sizes, int n_in,
                              void* d_out, int out_size, void* d_ws, size_t ws_size,
                              hipStream_t stream)
{
    const float* x   = (const float*)d_in[0];
    const float* Wq  = (const float*)d_in[1];
    const float* bq  = (const float*)d_in[2];
    const float* Wk  = (const float*)d_in[3];
    const float* bk  = (const float*)d_in[4];
    const float* Wv  = (const float*)d_in[5];
    const float* bv  = (const float*)d_in[6];
    const float* Wp  = (const float*)d_in[7];
    const float* bp  = (const float*)d_in[8];
    const float* W1  = (const float*)d_in[9];
    const float* b1  = (const float*)d_in[10];
    const float* W2  = (const float*)d_in[11];
    const float* b2  = (const float*)d_in[12];
    const float* g1  = (const float*)d_in[13];
    const float* be1 = (const float*)d_in[14];
    const float* g2  = (const float*)d_in[15];
    const float* be2 = (const float*)d_in[16];

    char* ws = (char*)d_ws;
    const size_t MB = 1024 * 1024;
    u16*   ln_buf = (u16*)(ws);              //  8 MB  [4096][1024] bf16
    u16*   qkv    = (u16*)(ws + 8 * MB);     // 24 MB  [4096][3072] bf16
    u16*   attn_o = (u16*)(ws + 32 * MB);    //  8 MB  [4096][1024] bf16
    float* x1     = (float*)(ws + 40 * MB);  // 16 MB  [4096][1024] f32
    u16*   hbuf   = (u16*)(ws + 56 * MB);    // 32 MB  [4096][4096] bf16
    u16*   wqkvT  = (u16*)(ws + 88 * MB);    //  6 MB  [3072][1024] bf16
    u16*   wpT    = (u16*)(ws + 94 * MB);    //  2 MB  [1024][1024] bf16
    u16*   w1T    = (u16*)(ws + 96 * MB);    //  8 MB  [4096][1024] bf16
    u16*   w2T    = (u16*)(ws + 104 * MB);   //  8 MB  [1024][4096] bf16

    transpose_w<<<dim3(32, 32), 256, 0, stream>>>(Wq, wqkvT, 1024, 1024);
    transpose_w<<<dim3(32, 32), 256, 0, stream>>>(Wk, wqkvT + 1024 * 1024, 1024, 1024);
    transpose_w<<<dim3(32, 32), 256, 0, stream>>>(Wv, wqkvT + 2 * 1024 * 1024, 1024, 1024);
    transpose_w<<<dim3(32, 32), 256, 0, stream>>>(Wp, wpT, 1024, 1024);
    transpose_w<<<dim3(128, 32), 256, 0, stream>>>(W1, w1T, 1024, 4096);
    transpose_w<<<dim3(32, 128), 256, 0, stream>>>(W2, w2T, 4096, 1024);

    ln_bf16<<<4096, 256, 0, stream>>>(x, g1, be1, ln_buf);
    gemm_bf16<0><<<dim3(24, 32), 256, 0, stream>>>(
        ln_buf, wqkvT, bq, bk, bv, nullptr, qkv, 4096, 3072, 1024);
    attn_fwd<<<dim3(16, 64), 256, 0, stream>>>(qkv, attn_o);
    gemm_bf16<1><<<dim3(8, 32), 256, 0, stream>>>(
        attn_o, wpT, bp, nullptr, nullptr, x, x1, 4096, 1024, 1024);
    ln_bf16<<<4096, 256, 0, stream>>>(x1, g2, be2, ln_buf);
    gemm_bf16<2><<<dim3(32, 32), 256, 0, stream>>>(
        ln_buf, w1T, b1, nullptr, nullptr, nullptr, hbuf, 4096, 4096, 1024);
    gemm_bf16<1><<<dim3(8, 32), 256, 0, stream>>>(
        hbuf, w2T, b2, nullptr, nullptr, x1, (float*)d_out, 4096, 1024, 4096);
}

// Round 2
// 249.298 us; speedup vs baseline: 1.2354x; 1.2354x over previous
//
#include <hip/hip_runtime.h>
#include <hip/hip_bf16.h>

typedef __attribute__((ext_vector_type(8))) __bf16 bf16x8;
typedef __attribute__((ext_vector_type(4))) float f32x4;
typedef __attribute__((ext_vector_type(4))) unsigned short u16x4;
typedef unsigned short u16;

#define AS3(p) ((__attribute__((address_space(3))) void*)(p))
#define AS1(p) ((const __attribute__((address_space(1))) void*)(p))

__device__ __forceinline__ u16 f2b(float f) {
    __hip_bfloat16 h = __float2bfloat16(f);
    return __builtin_bit_cast(u16, h);
}

// ---------------------------------------------------------------------------
// Weight transpose: W [K][N] fp32 -> WT [N][K] bf16 (tiled, padded LDS)
// ---------------------------------------------------------------------------
__global__ __launch_bounds__(256) void transpose_w(
    const float* __restrict__ W, u16* __restrict__ WT, int K, int N)
{
    __shared__ u16 tile[32][33];
    const int tx = threadIdx.x & 31, ty = threadIdx.x >> 5;
    const int n0 = blockIdx.x * 32, k0 = blockIdx.y * 32;
    #pragma unroll
    for (int p = 0; p < 4; ++p)
        tile[ty + p * 8][tx] = f2b(W[(size_t)(k0 + ty + p * 8) * N + n0 + tx]);
    __syncthreads();
    #pragma unroll
    for (int p = 0; p < 4; ++p)
        WT[(size_t)(n0 + ty + p * 8) * K + k0 + tx] = tile[tx][ty + p * 8];
}

// ---------------------------------------------------------------------------
// LayerNorm: x fp32 [rows][1024] -> y bf16, one block per row
// ---------------------------------------------------------------------------
__global__ __launch_bounds__(256) void ln_bf16(
    const float* __restrict__ xin, const float* __restrict__ gam,
    const float* __restrict__ bet, u16* __restrict__ yout)
{
    __shared__ float red[8];
    const int row = blockIdx.x, tid = threadIdx.x;
    float4 v = ((const float4*)(xin + (size_t)row * 1024))[tid];
    float s = v.x + v.y + v.z + v.w;
    #pragma unroll
    for (int o = 32; o > 0; o >>= 1) s += __shfl_xor(s, o, 64);
    if ((tid & 63) == 0) red[tid >> 6] = s;
    __syncthreads();
    const float mu = (red[0] + red[1] + red[2] + red[3]) * (1.f / 1024.f);
    const float dx = v.x - mu, dy = v.y - mu, dz = v.z - mu, dw = v.w - mu;
    float sq = dx * dx + dy * dy + dz * dz + dw * dw;
    #pragma unroll
    for (int o = 32; o > 0; o >>= 1) sq += __shfl_xor(sq, o, 64);
    if ((tid & 63) == 0) red[4 + (tid >> 6)] = sq;
    __syncthreads();
    const float var = (red[4] + red[5] + red[6] + red[7]) * (1.f / 1024.f);
    const float inv = rsqrtf(var + 1e-5f);
    const float4 G = ((const float4*)gam)[tid];
    const float4 Bt = ((const float4*)bet)[tid];
    u16x4 o;
    o[0] = f2b(dx * inv * G.x + Bt.x);
    o[1] = f2b(dy * inv * G.y + Bt.y);
    o[2] = f2b(dz * inv * G.z + Bt.z);
    o[3] = f2b(dw * inv * G.w + Bt.w);
    ((u16x4*)(yout + (size_t)row * 1024))[tid] = o;
}

// ---------------------------------------------------------------------------
// GEMM: C[M][N] = A[M][K](bf16) @ BT[N][K]^T(bf16) + epilogue
// 128 x BN tile, BK=64, 4 waves (2x2), global_load_lds w=16,
// XOR-swizzled LDS via pre-swizzled global source, 2 barriers/K-step.
// BN=64 variant doubles grid for N=1024 shapes (occupancy fix).
// MODE 0: bias(3-way QKV select), out bf16
// MODE 1: bias + residual(fp32), out fp32
// MODE 2: bias + exact GELU, out bf16
// ---------------------------------------------------------------------------
template <int MODE, int BN>
__global__ __launch_bounds__(256) void gemm_bf16(
    const u16* __restrict__ A, const u16* __restrict__ BT,
    const float* __restrict__ b0, const float* __restrict__ b1,
    const float* __restrict__ b2, const float* __restrict__ resid,
    void* __restrict__ outp, int M, int N, int K)
{
    constexpr int NI = BN / 32;               // per-wave n-fragments
    __shared__ u16 Asm[128 * 64];
    __shared__ u16 Bsm[BN * 64];
    const int tid = threadIdx.x;
    const int lane = tid & 63, wid = tid >> 6;
    const int bn0 = blockIdx.x * BN, bm0 = blockIdx.y * 128;
    const int wm = wid >> 1, wn = wid & 1;
    const int g = lane >> 4, l16 = lane & 15;
    const int srow = lane >> 3;              // 0..7 within 8-row chunk
    const int sslot = (lane & 7) ^ srow;     // inverse-swizzled k-slot (16B units)

    f32x4 acc[4][NI] = {};

    const u16* aBase = A + (size_t)bm0 * K + sslot * 8;
    const u16* bBase = BT + (size_t)bn0 * K + sslot * 8;

    for (int kt = 0; kt < K; kt += 64) {
        __syncthreads();
        #pragma unroll
        for (int j = 0; j < 4; ++j) {
            const int inst = wid * 4 + j;          // 16 insts, 4/wave
            const int row = inst * 8 + srow;       // 0..127
            __builtin_amdgcn_global_load_lds(AS1(aBase + (size_t)row * K + kt),
                                             AS3(Asm + inst * 512), 16, 0, 0);
        }
        #pragma unroll
        for (int j = 0; j < NI; ++j) {
            const int inst = wid * NI + j;         // BN/8 insts
            const int row = inst * 8 + srow;       // 0..BN-1
            __builtin_amdgcn_global_load_lds(AS1(bBase + (size_t)row * K + kt),
                                             AS3(Bsm + inst * 512), 16, 0, 0);
        }
        __syncthreads();
        #pragma unroll
        for (int ks = 0; ks < 2; ++ks) {
            bf16x8 af[4], bfr[NI];
            #pragma unroll
            for (int mi = 0; mi < 4; ++mi) {
                const int r = wm * 64 + mi * 16 + l16;
                const int slot = (g + 4 * ks) ^ (r & 7);   // swizzled read
                af[mi] = *(const bf16x8*)(Asm + r * 64 + slot * 8);
            }
            #pragma unroll
            for (int ni = 0; ni < NI; ++ni) {
                const int r = wn * (BN / 2) + ni * 16 + l16;
                const int slot = (g + 4 * ks) ^ (r & 7);
                bfr[ni] = *(const bf16x8*)(Bsm + r * 64 + slot * 8);
            }
            #pragma unroll
            for (int mi = 0; mi < 4; ++mi)
                #pragma unroll
                for (int ni = 0; ni < NI; ++ni)
                    acc[mi][ni] = __builtin_amdgcn_mfma_f32_16x16x32_bf16(
                        af[mi], bfr[ni], acc[mi][ni], 0, 0, 0);
        }
    }

    #pragma unroll
    for (int mi = 0; mi < 4; ++mi) {
        #pragma unroll
        for (int ni = 0; ni < NI; ++ni) {
            #pragma unroll
            for (int j = 0; j < 4; ++j) {
                const int m = bm0 + wm * 64 + mi * 16 + g * 4 + j;  // C/D: row=4g+j
                const int n = bn0 + wn * (BN / 2) + ni * 16 + l16;  // C/D: col=l16
                float v = acc[mi][ni][j];
                if constexpr (MODE == 0) {
                    const float bias = (n < 1024) ? b0[n]
                                      : (n < 2048) ? b1[n - 1024] : b2[n - 2048];
                    ((u16*)outp)[(size_t)m * N + n] = f2b(v + bias);
                } else if constexpr (MODE == 1) {
                    ((float*)outp)[(size_t)m * N + n] =
                        v + b0[n] + resid[(size_t)m * N + n];
                } else {
                    v += b0[n];
                    v = 0.5f * v * (1.0f + erff(v * 0.70710678118654752f));
                    ((u16*)outp)[(size_t)m * N + n] = f2b(v);
                }
            }
        }
    }
}

// ---------------------------------------------------------------------------
// Flash attention (causal): qkv bf16 [4096][3072] (q|k|v per row, head-major)
// v2: each block processes paired q-tiles {x, 15-x} -> uniform 17 tile-units
// (fixes causal load imbalance); T14 async staging (global->reg issued under
// previous tile's compute, reg->LDS after barrier); V^T via in-register 4x4
// transpose + u16x4 stores (kills the 16-way scalar-store bank conflict);
// same-(b,h) blocks grouped on one XCD for KV L2 locality.
// Grid (8, 64), 4 waves x 16 q-rows.
// ---------------------------------------------------------------------------
__global__ __launch_bounds__(256) void attn_fwd(
    const u16* __restrict__ qkv, u16* __restrict__ outp)
{
    __shared__ u16 Ksm[64 * 72];        // K tile [kv][d], +8 pad
    __shared__ u16 Vsm[64 * 72];        // V^T tile [d][kv], +8 pad
    __shared__ u16 Psm[4][16 * 72];     // per-wave P [16 q][64 kv], +8 pad
    const int tid = threadIdx.x, lane = tid & 63, w = tid >> 6;
    // XCD-grouping swizzle: all 8 q-blocks of one (b,h) share lin%8 -> same XCD
    const int lin = blockIdx.y * 8 + blockIdx.x;        // 0..511
    const int xq = (lin >> 3) & 7;                      // base q-pair index 0..7
    const int bh = (((lin >> 6) & 7) << 3) | (lin & 7); // 0..63
    const int b = bh >> 4, h = bh & 15;
    const int g = lane >> 4, l16 = lane & 15;
    const int skv = tid >> 4;            // 0..15 staging row group
    const int sd4 = (tid & 15) * 4;      // 0..60 staging d offset

    const u16* kvb = qkv + (size_t)(b * 1024) * 3072 + 1024 + h * 64; // K base

    u16x4 kreg[4], vreg[4];
    auto issue = [&](int kv0) {
        const u16* kb = kvb + (size_t)kv0 * 3072;
        #pragma unroll
        for (int i = 0; i < 4; ++i)
            kreg[i] = *(const u16x4*)(kb + (size_t)(skv + 16 * i) * 3072 + sd4);
        #pragma unroll
        for (int i = 0; i < 4; ++i)
            vreg[i] = *(const u16x4*)(kb + (size_t)(4 * skv + i) * 3072 + 1024 + sd4);
    };

    #pragma unroll
    for (int half = 0; half < 2; ++half) {
        const int qt = half ? (15 - xq) : xq;
        const int q0 = qt * 64;

        bf16x8 qf0, qf1;   // Q fragment: row=l16, k(d)=8g(+32)
        {
            const u16* qp = qkv + (size_t)(b * 1024 + q0 + w * 16 + l16) * 3072
                            + h * 64 + g * 8;
            qf0 = *(const bf16x8*)qp;
            qf1 = *(const bf16x8*)(qp + 32);
        }
        float m_run[4] = {-1e30f, -1e30f, -1e30f, -1e30f};
        float l_run[4] = {0.f, 0.f, 0.f, 0.f};
        f32x4 oacc[4] = {};

        issue(0);  // prologue loads for tile 0

        for (int kvt = 0; kvt <= qt; ++kvt) {
            const int kv0 = kvt * 64;
            __syncthreads();   // all waves done reading previous LDS tile
            // reg -> LDS (compiler inserts vmcnt waits on kreg/vreg here)
            #pragma unroll
            for (int i = 0; i < 4; ++i)
                *(u16x4*)(Ksm + (skv + 16 * i) * 72 + sd4) = kreg[i];
            #pragma unroll
            for (int j = 0; j < 4; ++j) {
                u16x4 t;
                t[0] = vreg[0][j]; t[1] = vreg[1][j];
                t[2] = vreg[2][j]; t[3] = vreg[3][j];
                *(u16x4*)(Vsm + (sd4 + j) * 72 + 4 * skv) = t;
            }
            __syncthreads();   // tile visible to all waves
            if (kvt < qt) issue(kv0 + 64);   // next tile loads fly under compute

            // S = Q K^T  (4 kv-column tiles of 16)
            f32x4 s[4];
            #pragma unroll
            for (int t = 0; t < 4; ++t) {
                const bf16x8 kf0 = *(const bf16x8*)(Ksm + (t * 16 + l16) * 72 + g * 8);
                const bf16x8 kf1 = *(const bf16x8*)(Ksm + (t * 16 + l16) * 72 + 32 + g * 8);
                f32x4 z = {};
                z = __builtin_amdgcn_mfma_f32_16x16x32_bf16(qf0, kf0, z, 0, 0, 0);
                z = __builtin_amdgcn_mfma_f32_16x16x32_bf16(qf1, kf1, z, 0, 0, 0);
                s[t] = z;
            }
            // scale + causal mask + row max
            float mx[4] = {-1e30f, -1e30f, -1e30f, -1e30f};
            #pragma unroll
            for (int t = 0; t < 4; ++t)
                #pragma unroll
                for (int j = 0; j < 4; ++j) {
                    const int qrow = q0 + w * 16 + g * 4 + j;
                    const int kvc = kv0 + t * 16 + l16;
                    float v = s[t][j] * 0.125f;
                    if (kvc > qrow) v = -1e30f;
                    s[t][j] = v;
                    mx[j] = fmaxf(mx[j], v);
                }
            #pragma unroll
            for (int o = 1; o < 16; o <<= 1)
                #pragma unroll
                for (int j = 0; j < 4; ++j)
                    mx[j] = fmaxf(mx[j], __shfl_xor(mx[j], o, 16));
            float alpha[4], rs[4];
            #pragma unroll
            for (int j = 0; j < 4; ++j) {
                const float mn = fmaxf(m_run[j], mx[j]);
                alpha[j] = __expf(m_run[j] - mn);
                m_run[j] = mn;
                rs[j] = 0.f;
            }
            #pragma unroll
            for (int t = 0; t < 4; ++t)
                #pragma unroll
                for (int j = 0; j < 4; ++j) {
                    const float p = __expf(s[t][j] - m_run[j]);
                    s[t][j] = p;
                    rs[j] += p;
                }
            #pragma unroll
            for (int o = 1; o < 16; o <<= 1)
                #pragma unroll
                for (int j = 0; j < 4; ++j)
                    rs[j] += __shfl_xor(rs[j], o, 16);
            #pragma unroll
            for (int j = 0; j < 4; ++j)
                l_run[j] = l_run[j] * alpha[j] + rs[j];
            #pragma unroll
            for (int dt = 0; dt < 4; ++dt)
                #pragma unroll
                for (int j = 0; j < 4; ++j)
                    oacc[dt][j] *= alpha[j];
            // P -> LDS (C-layout) -> A-fragment layout (per-wave buffer)
            #pragma unroll
            for (int t = 0; t < 4; ++t)
                #pragma unroll
                for (int j = 0; j < 4; ++j)
                    Psm[w][(g * 4 + j) * 72 + t * 16 + l16] = f2b(s[t][j]);
            const bf16x8 pf0 = *(const bf16x8*)(&Psm[w][l16 * 72 + g * 8]);
            const bf16x8 pf1 = *(const bf16x8*)(&Psm[w][l16 * 72 + 32 + g * 8]);
            // O += P V
            #pragma unroll
            for (int dt = 0; dt < 4; ++dt) {
                const bf16x8 vf0 = *(const bf16x8*)(Vsm + (dt * 16 + l16) * 72 + g * 8);
                const bf16x8 vf1 = *(const bf16x8*)(Vsm + (dt * 16 + l16) * 72 + 32 + g * 8);
                oacc[dt] = __builtin_amdgcn_mfma_f32_16x16x32_bf16(pf0, vf0, oacc[dt], 0, 0, 0);
                oacc[dt] = __builtin_amdgcn_mfma_f32_16x16x32_bf16(pf1, vf1, oacc[dt], 0, 0, 0);
            }
        }
        #pragma unroll
        for (int dt = 0; dt < 4; ++dt)
            #pragma unroll
            for (int j = 0; j < 4; ++j) {
                const int m = b * 1024 + q0 + w * 16 + g * 4 + j;
                const int col = h * 64 + dt * 16 + l16;
                outp[(size_t)m * 1024 + col] = f2b(oacc[dt][j] / l_run[j]);
            }
    }
}

// ---------------------------------------------------------------------------
extern "C" void kernel_launch(void* const* d_in, const int* in_sizes, int n_in,
                              void* d_out, int out_size, void* d_ws, size_t ws_size,
                              hipStream_t stream)
{
    const float* x   = (const float*)d_in[0];
    const float* Wq  = (const float*)d_in[1];
    const float* bq  = (const float*)d_in[2];
    const float* Wk  = (const float*)d_in[3];
    const float* bk  = (const float*)d_in[4];
    const float* Wv  = (const float*)d_in[5];
    const float* bv  = (const float*)d_in[6];
    const float* Wp  = (const float*)d_in[7];
    const float* bp  = (const float*)d_in[8];
    const float* W1  = (const float*)d_in[9];
    const float* b1  = (const float*)d_in[10];
    const float* W2  = (const float*)d_in[11];
    const float* b2  = (const float*)d_in[12];
    const float* g1  = (const float*)d_in[13];
    const float* be1 = (const float*)d_in[14];
    const float* g2  = (const float*)d_in[15];
    const float* be2 = (const float*)d_in[16];

    char* ws = (char*)d_ws;
    const size_t MB = 1024 * 1024;
    u16*   ln_buf = (u16*)(ws);              //  8 MB  [4096][1024] bf16
    u16*   qkv    = (u16*)(ws + 8 * MB);     // 24 MB  [4096][3072] bf16
    u16*   attn_o = (u16*)(ws + 32 * MB);    //  8 MB  [4096][1024] bf16
    float* x1     = (float*)(ws + 40 * MB);  // 16 MB  [4096][1024] f32
    u16*   hbuf   = (u16*)(ws + 56 * MB);    // 32 MB  [4096][4096] bf16
    u16*   wqkvT  = (u16*)(ws + 88 * MB);    //  6 MB  [3072][1024] bf16
    u16*   wpT    = (u16*)(ws + 94 * MB);    //  2 MB  [1024][1024] bf16
    u16*   w1T    = (u16*)(ws + 96 * MB);    //  8 MB  [4096][1024] bf16
    u16*   w2T    = (u16*)(ws + 104 * MB);   //  8 MB  [1024][4096] bf16

    transpose_w<<<dim3(32, 32), 256, 0, stream>>>(Wq, wqkvT, 1024, 1024);
    transpose_w<<<dim3(32, 32), 256, 0, stream>>>(Wk, wqkvT + 1024 * 1024, 1024, 1024);
    transpose_w<<<dim3(32, 32), 256, 0, stream>>>(Wv, wqkvT + 2 * 1024 * 1024, 1024, 1024);
    transpose_w<<<dim3(32, 32), 256, 0, stream>>>(Wp, wpT, 1024, 1024);
    transpose_w<<<dim3(128, 32), 256, 0, stream>>>(W1, w1T, 1024, 4096);
    transpose_w<<<dim3(32, 128), 256, 0, stream>>>(W2, w2T, 4096, 1024);

    ln_bf16<<<4096, 256, 0, stream>>>(x, g1, be1, ln_buf);
    gemm_bf16<0, 128><<<dim3(24, 32), 256, 0, stream>>>(
        ln_buf, wqkvT, bq, bk, bv, nullptr, qkv, 4096, 3072, 1024);
    attn_fwd<<<dim3(8, 64), 256, 0, stream>>>(qkv, attn_o);
    gemm_bf16<1, 64><<<dim3(16, 32), 256, 0, stream>>>(
        attn_o, wpT, bp, nullptr, nullptr, x, x1, 4096, 1024, 1024);
    ln_bf16<<<4096, 256, 0, stream>>>(x1, g2, be2, ln_buf);
    gemm_bf16<2, 128><<<dim3(32, 32), 256, 0, stream>>>(
        ln_buf, w1T, b1, nullptr, nullptr, nullptr, hbuf, 4096, 4096, 1024);
    gemm_bf16<1, 64><<<dim3(16, 32), 256, 0, stream>>>(
        hbuf, w2T, b2, nullptr, nullptr, x1, (float*)d_out, 4096, 1024, 4096);
}

// Round 3
// 241.485 us; speedup vs baseline: 1.2754x; 1.0324x over previous
//
#include <hip/hip_runtime.h>
#include <hip/hip_bf16.h>

typedef __attribute__((ext_vector_type(8))) __bf16 bf16x8;
typedef __attribute__((ext_vector_type(4))) float f32x4;
typedef __attribute__((ext_vector_type(4))) unsigned short u16x4;
typedef unsigned short u16;

#define AS3(p) ((__attribute__((address_space(3))) void*)(p))
#define AS1(p) ((const __attribute__((address_space(1))) void*)(p))

__device__ __forceinline__ u16 f2b(float f) {
    __hip_bfloat16 h = __float2bfloat16(f);
    return __builtin_bit_cast(u16, h);
}

// Exact-enough GELU: Abramowitz-Stegun 7.1.26 erf (max abs err 1.5e-7)
__device__ __forceinline__ float gelu_exact(float v) {
    const float z = v * 0.70710678118654752f;
    const float a = fabsf(z);
    const float t = __builtin_amdgcn_rcpf(1.0f + 0.3275911f * a);
    float p = 1.061405429f;
    p = p * t - 1.453152027f;
    p = p * t + 1.421413741f;
    p = p * t - 0.284496736f;
    p = p * t + 0.254829592f;
    p = p * t;
    float erfv = 1.0f - p * __expf(-a * a);
    erfv = copysignf(erfv, z);
    return 0.5f * v * (1.0f + erfv);
}

// ---------------------------------------------------------------------------
// Weight transpose: W [K][N] fp32 -> WT [N][K] bf16 (tiled, padded LDS)
// ---------------------------------------------------------------------------
__global__ __launch_bounds__(256) void transpose_w(
    const float* __restrict__ W, u16* __restrict__ WT, int K, int N)
{
    __shared__ u16 tile[32][33];
    const int tx = threadIdx.x & 31, ty = threadIdx.x >> 5;
    const int n0 = blockIdx.x * 32, k0 = blockIdx.y * 32;
    #pragma unroll
    for (int p = 0; p < 4; ++p)
        tile[ty + p * 8][tx] = f2b(W[(size_t)(k0 + ty + p * 8) * N + n0 + tx]);
    __syncthreads();
    #pragma unroll
    for (int p = 0; p < 4; ++p)
        WT[(size_t)(n0 + ty + p * 8) * K + k0 + tx] = tile[tx][ty + p * 8];
}

// ---------------------------------------------------------------------------
// LayerNorm: x fp32 [rows][1024] -> y bf16, one block per row
// ---------------------------------------------------------------------------
__global__ __launch_bounds__(256) void ln_bf16(
    const float* __restrict__ xin, const float* __restrict__ gam,
    const float* __restrict__ bet, u16* __restrict__ yout)
{
    __shared__ float red[8];
    const int row = blockIdx.x, tid = threadIdx.x;
    float4 v = ((const float4*)(xin + (size_t)row * 1024))[tid];
    float s = v.x + v.y + v.z + v.w;
    #pragma unroll
    for (int o = 32; o > 0; o >>= 1) s += __shfl_xor(s, o, 64);
    if ((tid & 63) == 0) red[tid >> 6] = s;
    __syncthreads();
    const float mu = (red[0] + red[1] + red[2] + red[3]) * (1.f / 1024.f);
    const float dx = v.x - mu, dy = v.y - mu, dz = v.z - mu, dw = v.w - mu;
    float sq = dx * dx + dy * dy + dz * dz + dw * dw;
    #pragma unroll
    for (int o = 32; o > 0; o >>= 1) sq += __shfl_xor(sq, o, 64);
    if ((tid & 63) == 0) red[4 + (tid >> 6)] = sq;
    __syncthreads();
    const float var = (red[4] + red[5] + red[6] + red[7]) * (1.f / 1024.f);
    const float inv = rsqrtf(var + 1e-5f);
    const float4 G = ((const float4*)gam)[tid];
    const float4 Bt = ((const float4*)bet)[tid];
    u16x4 o;
    o[0] = f2b(dx * inv * G.x + Bt.x);
    o[1] = f2b(dy * inv * G.y + Bt.y);
    o[2] = f2b(dz * inv * G.z + Bt.z);
    o[3] = f2b(dw * inv * G.w + Bt.w);
    ((u16x4*)(yout + (size_t)row * 1024))[tid] = o;
}

// ---------------------------------------------------------------------------
// GEMM: C[M][N] = A[M][K](bf16) @ BT[N][K]^T(bf16) + epilogue
// v3: T3-minimum 2-phase pipeline — double-buffered LDS, STAGE(t+1) issued
// BEFORE compute(t), ONE barrier per K-step (its implicit vmcnt(0) drain
// lands after the MFMAs -> HBM latency hides under compute).
// grid.x = M-blocks (same-A-panel blocks share an XCD L2), grid.y = N-blocks.
// MODE 0: bias(3-way QKV select), out bf16
// MODE 1: bias + residual(fp32), out fp32
// MODE 2: bias + exact GELU, out bf16
// ---------------------------------------------------------------------------
template <int MODE, int BN>
__global__ __launch_bounds__(256) void gemm_bf16(
    const u16* __restrict__ A, const u16* __restrict__ BT,
    const float* __restrict__ b0, const float* __restrict__ b1,
    const float* __restrict__ b2, const float* __restrict__ resid,
    void* __restrict__ outp, int M, int N, int K)
{
    constexpr int NI = BN / 32;               // per-wave n-fragments
    __shared__ u16 Asm[2][128 * 64];
    __shared__ u16 Bsm[2][BN * 64];
    const int tid = threadIdx.x;
    const int lane = tid & 63, wid = tid >> 6;
    const int bm0 = blockIdx.x * 128, bn0 = blockIdx.y * BN;   // x = M!
    const int wm = wid >> 1, wn = wid & 1;
    const int g = lane >> 4, l16 = lane & 15;
    const int srow = lane >> 3;              // 0..7 within 8-row chunk
    const int sslot = (lane & 7) ^ srow;     // inverse-swizzled k-slot (16B units)

    f32x4 acc[4][NI] = {};

    const u16* aBase = A + (size_t)bm0 * K + sslot * 8;
    const u16* bBase = BT + (size_t)bn0 * K + sslot * 8;

    auto stage = [&](int kt, int buf) {
        #pragma unroll
        for (int j = 0; j < 4; ++j) {
            const int inst = wid * 4 + j;          // 16 insts, 4/wave
            const int row = inst * 8 + srow;       // 0..127
            __builtin_amdgcn_global_load_lds(AS1(aBase + (size_t)row * K + kt),
                                             AS3(&Asm[buf][inst * 512]), 16, 0, 0);
        }
        #pragma unroll
        for (int j = 0; j < NI; ++j) {
            const int inst = wid * NI + j;         // BN/8 insts
            const int row = inst * 8 + srow;       // 0..BN-1
            __builtin_amdgcn_global_load_lds(AS1(bBase + (size_t)row * K + kt),
                                             AS3(&Bsm[buf][inst * 512]), 16, 0, 0);
        }
    };

    stage(0, 0);
    __syncthreads();          // barrier drain: tile 0 resident
    int cur = 0;

    for (int kt = 0; kt < K; kt += 64) {
        if (kt + 64 < K) stage(kt + 64, cur ^ 1);   // prefetch flies under MFMA
        #pragma unroll
        for (int ks = 0; ks < 2; ++ks) {
            bf16x8 af[4], bfr[NI];
            #pragma unroll
            for (int mi = 0; mi < 4; ++mi) {
                const int r = wm * 64 + mi * 16 + l16;
                const int slot = (g + 4 * ks) ^ (r & 7);   // swizzled read
                af[mi] = *(const bf16x8*)(&Asm[cur][r * 64 + slot * 8]);
            }
            #pragma unroll
            for (int ni = 0; ni < NI; ++ni) {
                const int r = wn * (BN / 2) + ni * 16 + l16;
                const int slot = (g + 4 * ks) ^ (r & 7);
                bfr[ni] = *(const bf16x8*)(&Bsm[cur][r * 64 + slot * 8]);
            }
            #pragma unroll
            for (int mi = 0; mi < 4; ++mi)
                #pragma unroll
                for (int ni = 0; ni < NI; ++ni)
                    acc[mi][ni] = __builtin_amdgcn_mfma_f32_16x16x32_bf16(
                        af[mi], bfr[ni], acc[mi][ni], 0, 0, 0);
        }
        __syncthreads();      // single barrier: drains prefetch AFTER compute
        cur ^= 1;
    }

    #pragma unroll
    for (int mi = 0; mi < 4; ++mi) {
        #pragma unroll
        for (int ni = 0; ni < NI; ++ni) {
            #pragma unroll
            for (int j = 0; j < 4; ++j) {
                const int m = bm0 + wm * 64 + mi * 16 + g * 4 + j;  // C/D: row=4g+j
                const int n = bn0 + wn * (BN / 2) + ni * 16 + l16;  // C/D: col=l16
                float v = acc[mi][ni][j];
                if constexpr (MODE == 0) {
                    const float bias = (n < 1024) ? b0[n]
                                      : (n < 2048) ? b1[n - 1024] : b2[n - 2048];
                    ((u16*)outp)[(size_t)m * N + n] = f2b(v + bias);
                } else if constexpr (MODE == 1) {
                    ((float*)outp)[(size_t)m * N + n] =
                        v + b0[n] + resid[(size_t)m * N + n];
                } else {
                    ((u16*)outp)[(size_t)m * N + n] = f2b(gelu_exact(v + b0[n]));
                }
            }
        }
    }
}

// ---------------------------------------------------------------------------
// Flash attention (causal): qkv bf16 [4096][3072] (q|k|v per row, head-major)
// Paired q-tiles {x, 15-x} -> uniform load; T14 async staging; V^T via
// in-register 4x4 transpose; same-(b,h) blocks grouped per XCD.
// Grid (8, 64), 4 waves x 16 q-rows.
// ---------------------------------------------------------------------------
__global__ __launch_bounds__(256) void attn_fwd(
    const u16* __restrict__ qkv, u16* __restrict__ outp)
{
    __shared__ u16 Ksm[64 * 72];        // K tile [kv][d], +8 pad
    __shared__ u16 Vsm[64 * 72];        // V^T tile [d][kv], +8 pad
    __shared__ u16 Psm[4][16 * 72];     // per-wave P [16 q][64 kv], +8 pad
    const int tid = threadIdx.x, lane = tid & 63, w = tid >> 6;
    const int lin = blockIdx.y * 8 + blockIdx.x;        // 0..511
    const int xq = (lin >> 3) & 7;                      // base q-pair index 0..7
    const int bh = (((lin >> 6) & 7) << 3) | (lin & 7); // 0..63
    const int b = bh >> 4, h = bh & 15;
    const int g = lane >> 4, l16 = lane & 15;
    const int skv = tid >> 4;            // 0..15 staging row group
    const int sd4 = (tid & 15) * 4;      // 0..60 staging d offset

    const u16* kvb = qkv + (size_t)(b * 1024) * 3072 + 1024 + h * 64; // K base

    u16x4 kreg[4], vreg[4];
    auto issue = [&](int kv0) {
        const u16* kb = kvb + (size_t)kv0 * 3072;
        #pragma unroll
        for (int i = 0; i < 4; ++i)
            kreg[i] = *(const u16x4*)(kb + (size_t)(skv + 16 * i) * 3072 + sd4);
        #pragma unroll
        for (int i = 0; i < 4; ++i)
            vreg[i] = *(const u16x4*)(kb + (size_t)(4 * skv + i) * 3072 + 1024 + sd4);
    };

    #pragma unroll
    for (int half = 0; half < 2; ++half) {
        const int qt = half ? (15 - xq) : xq;
        const int q0 = qt * 64;

        bf16x8 qf0, qf1;   // Q fragment: row=l16, k(d)=8g(+32)
        {
            const u16* qp = qkv + (size_t)(b * 1024 + q0 + w * 16 + l16) * 3072
                            + h * 64 + g * 8;
            qf0 = *(const bf16x8*)qp;
            qf1 = *(const bf16x8*)(qp + 32);
        }
        float m_run[4] = {-1e30f, -1e30f, -1e30f, -1e30f};
        float l_run[4] = {0.f, 0.f, 0.f, 0.f};
        f32x4 oacc[4] = {};

        issue(0);  // prologue loads for tile 0

        for (int kvt = 0; kvt <= qt; ++kvt) {
            const int kv0 = kvt * 64;
            __syncthreads();   // all waves done reading previous LDS tile
            #pragma unroll
            for (int i = 0; i < 4; ++i)
                *(u16x4*)(Ksm + (skv + 16 * i) * 72 + sd4) = kreg[i];
            #pragma unroll
            for (int j = 0; j < 4; ++j) {
                u16x4 t;
                t[0] = vreg[0][j]; t[1] = vreg[1][j];
                t[2] = vreg[2][j]; t[3] = vreg[3][j];
                *(u16x4*)(Vsm + (sd4 + j) * 72 + 4 * skv) = t;
            }
            __syncthreads();   // tile visible to all waves
            if (kvt < qt) issue(kv0 + 64);   // next tile loads fly under compute

            // S = Q K^T  (4 kv-column tiles of 16)
            f32x4 s[4];
            #pragma unroll
            for (int t = 0; t < 4; ++t) {
                const bf16x8 kf0 = *(const bf16x8*)(Ksm + (t * 16 + l16) * 72 + g * 8);
                const bf16x8 kf1 = *(const bf16x8*)(Ksm + (t * 16 + l16) * 72 + 32 + g * 8);
                f32x4 z = {};
                z = __builtin_amdgcn_mfma_f32_16x16x32_bf16(qf0, kf0, z, 0, 0, 0);
                z = __builtin_amdgcn_mfma_f32_16x16x32_bf16(qf1, kf1, z, 0, 0, 0);
                s[t] = z;
            }
            // scale + causal mask + row max
            float mx[4] = {-1e30f, -1e30f, -1e30f, -1e30f};
            #pragma unroll
            for (int t = 0; t < 4; ++t)
                #pragma unroll
                for (int j = 0; j < 4; ++j) {
                    const int qrow = q0 + w * 16 + g * 4 + j;
                    const int kvc = kv0 + t * 16 + l16;
                    float v = s[t][j] * 0.125f;
                    if (kvc > qrow) v = -1e30f;
                    s[t][j] = v;
                    mx[j] = fmaxf(mx[j], v);
                }
            #pragma unroll
            for (int o = 1; o < 16; o <<= 1)
                #pragma unroll
                for (int j = 0; j < 4; ++j)
                    mx[j] = fmaxf(mx[j], __shfl_xor(mx[j], o, 16));
            float alpha[4], rs[4];
            #pragma unroll
            for (int j = 0; j < 4; ++j) {
                const float mn = fmaxf(m_run[j], mx[j]);
                alpha[j] = __expf(m_run[j] - mn);
                m_run[j] = mn;
                rs[j] = 0.f;
            }
            #pragma unroll
            for (int t = 0; t < 4; ++t)
                #pragma unroll
                for (int j = 0; j < 4; ++j) {
                    const float p = __expf(s[t][j] - m_run[j]);
                    s[t][j] = p;
                    rs[j] += p;
                }
            #pragma unroll
            for (int o = 1; o < 16; o <<= 1)
                #pragma unroll
                for (int j = 0; j < 4; ++j)
                    rs[j] += __shfl_xor(rs[j], o, 16);
            #pragma unroll
            for (int j = 0; j < 4; ++j)
                l_run[j] = l_run[j] * alpha[j] + rs[j];
            #pragma unroll
            for (int dt = 0; dt < 4; ++dt)
                #pragma unroll
                for (int j = 0; j < 4; ++j)
                    oacc[dt][j] *= alpha[j];
            // P -> LDS (C-layout) -> A-fragment layout (per-wave buffer)
            #pragma unroll
            for (int t = 0; t < 4; ++t)
                #pragma unroll
                for (int j = 0; j < 4; ++j)
                    Psm[w][(g * 4 + j) * 72 + t * 16 + l16] = f2b(s[t][j]);
            const bf16x8 pf0 = *(const bf16x8*)(&Psm[w][l16 * 72 + g * 8]);
            const bf16x8 pf1 = *(const bf16x8*)(&Psm[w][l16 * 72 + 32 + g * 8]);
            // O += P V
            #pragma unroll
            for (int dt = 0; dt < 4; ++dt) {
                const bf16x8 vf0 = *(const bf16x8*)(Vsm + (dt * 16 + l16) * 72 + g * 8);
                const bf16x8 vf1 = *(const bf16x8*)(Vsm + (dt * 16 + l16) * 72 + 32 + g * 8);
                oacc[dt] = __builtin_amdgcn_mfma_f32_16x16x32_bf16(pf0, vf0, oacc[dt], 0, 0, 0);
                oacc[dt] = __builtin_amdgcn_mfma_f32_16x16x32_bf16(pf1, vf1, oacc[dt], 0, 0, 0);
            }
        }
        #pragma unroll
        for (int dt = 0; dt < 4; ++dt)
            #pragma unroll
            for (int j = 0; j < 4; ++j) {
                const int m = b * 1024 + q0 + w * 16 + g * 4 + j;
                const int col = h * 64 + dt * 16 + l16;
                outp[(size_t)m * 1024 + col] = f2b(oacc[dt][j] / l_run[j]);
            }
    }
}

// ---------------------------------------------------------------------------
extern "C" void kernel_launch(void* const* d_in, const int* in_sizes, int n_in,
                              void* d_out, int out_size, void* d_ws, size_t ws_size,
                              hipStream_t stream)
{
    const float* x   = (const float*)d_in[0];
    const float* Wq  = (const float*)d_in[1];
    const float* bq  = (const float*)d_in[2];
    const float* Wk  = (const float*)d_in[3];
    const float* bk  = (const float*)d_in[4];
    const float* Wv  = (const float*)d_in[5];
    const float* bv  = (const float*)d_in[6];
    const float* Wp  = (const float*)d_in[7];
    const float* bp  = (const float*)d_in[8];
    const float* W1  = (const float*)d_in[9];
    const float* b1  = (const float*)d_in[10];
    const float* W2  = (const float*)d_in[11];
    const float* b2  = (const float*)d_in[12];
    const float* g1  = (const float*)d_in[13];
    const float* be1 = (const float*)d_in[14];
    const float* g2  = (const float*)d_in[15];
    const float* be2 = (const float*)d_in[16];

    char* ws = (char*)d_ws;
    const size_t MB = 1024 * 1024;
    u16*   ln_buf = (u16*)(ws);              //  8 MB  [4096][1024] bf16
    u16*   qkv    = (u16*)(ws + 8 * MB);     // 24 MB  [4096][3072] bf16
    u16*   attn_o = (u16*)(ws + 32 * MB);    //  8 MB  [4096][1024] bf16
    float* x1     = (float*)(ws + 40 * MB);  // 16 MB  [4096][1024] f32
    u16*   hbuf   = (u16*)(ws + 56 * MB);    // 32 MB  [4096][4096] bf16
    u16*   wqkvT  = (u16*)(ws + 88 * MB);    //  6 MB  [3072][1024] bf16
    u16*   wpT    = (u16*)(ws + 94 * MB);    //  2 MB  [1024][1024] bf16
    u16*   w1T    = (u16*)(ws + 96 * MB);    //  8 MB  [4096][1024] bf16
    u16*   w2T    = (u16*)(ws + 104 * MB);   //  8 MB  [1024][4096] bf16

    transpose_w<<<dim3(32, 32), 256, 0, stream>>>(Wq, wqkvT, 1024, 1024);
    transpose_w<<<dim3(32, 32), 256, 0, stream>>>(Wk, wqkvT + 1024 * 1024, 1024, 1024);
    transpose_w<<<dim3(32, 32), 256, 0, stream>>>(Wv, wqkvT + 2 * 1024 * 1024, 1024, 1024);
    transpose_w<<<dim3(32, 32), 256, 0, stream>>>(Wp, wpT, 1024, 1024);
    transpose_w<<<dim3(128, 32), 256, 0, stream>>>(W1, w1T, 1024, 4096);
    transpose_w<<<dim3(32, 128), 256, 0, stream>>>(W2, w2T, 4096, 1024);

    ln_bf16<<<4096, 256, 0, stream>>>(x, g1, be1, ln_buf);
    gemm_bf16<0, 128><<<dim3(32, 24), 256, 0, stream>>>(
        ln_buf, wqkvT, bq, bk, bv, nullptr, qkv, 4096, 3072, 1024);
    attn_fwd<<<dim3(8, 64), 256, 0, stream>>>(qkv, attn_o);
    gemm_bf16<1, 64><<<dim3(32, 16), 256, 0, stream>>>(
        attn_o, wpT, bp, nullptr, nullptr, x, x1, 4096, 1024, 1024);
    ln_bf16<<<4096, 256, 0, stream>>>(x1, g2, be2, ln_buf);
    gemm_bf16<2, 128><<<dim3(32, 32), 256, 0, stream>>>(
        ln_buf, w1T, b1, nullptr, nullptr, nullptr, hbuf, 4096, 4096, 1024);
    gemm_bf16<1, 64><<<dim3(32, 16), 256, 0, stream>>>(
        hbuf, w2T, b2, nullptr, nullptr, x1, (float*)d_out, 4096, 1024, 4096);
}

// Round 4
// 209.994 us; speedup vs baseline: 1.4667x; 1.1500x over previous
//
#include <hip/hip_runtime.h>
#include <hip/hip_bf16.h>

typedef __attribute__((ext_vector_type(8))) __bf16 bf16x8;
typedef __attribute__((ext_vector_type(4))) float f32x4;
typedef __attribute__((ext_vector_type(4))) unsigned short u16x4;
typedef unsigned short u16;

#define AS3(p) ((__attribute__((address_space(3))) void*)(p))
#define AS1(p) ((const __attribute__((address_space(1))) void*)(p))

__device__ __forceinline__ u16 f2b(float f) {
    __hip_bfloat16 h = __float2bfloat16(f);
    return __builtin_bit_cast(u16, h);
}

// Exact-enough GELU: Abramowitz-Stegun 7.1.26 erf (max abs err 1.5e-7)
__device__ __forceinline__ float gelu_exact(float v) {
    const float z = v * 0.70710678118654752f;
    const float a = fabsf(z);
    const float t = __builtin_amdgcn_rcpf(1.0f + 0.3275911f * a);
    float p = 1.061405429f;
    p = p * t - 1.453152027f;
    p = p * t + 1.421413741f;
    p = p * t - 0.284496736f;
    p = p * t + 0.254829592f;
    p = p * t;
    float erfv = 1.0f - p * __expf(-a * a);
    erfv = copysignf(erfv, z);
    return 0.5f * v * (1.0f + erfv);
}

// ---------------------------------------------------------------------------
// Weight transpose: W [K][N] fp32 -> WT [N][K] bf16 (tiled, padded LDS)
// ---------------------------------------------------------------------------
__global__ __launch_bounds__(256) void transpose_w(
    const float* __restrict__ W, u16* __restrict__ WT, int K, int N)
{
    __shared__ u16 tile[32][33];
    const int tx = threadIdx.x & 31, ty = threadIdx.x >> 5;
    const int n0 = blockIdx.x * 32, k0 = blockIdx.y * 32;
    #pragma unroll
    for (int p = 0; p < 4; ++p)
        tile[ty + p * 8][tx] = f2b(W[(size_t)(k0 + ty + p * 8) * N + n0 + tx]);
    __syncthreads();
    #pragma unroll
    for (int p = 0; p < 4; ++p)
        WT[(size_t)(n0 + ty + p * 8) * K + k0 + tx] = tile[tx][ty + p * 8];
}

// Fused Q/K/V weight transpose (one launch, z picks the matrix)
__global__ __launch_bounds__(256) void transpose_w3(
    const float* __restrict__ W0, const float* __restrict__ W1,
    const float* __restrict__ W2, u16* __restrict__ WT)
{
    __shared__ u16 tile[32][33];
    const int z = blockIdx.z;
    const float* W = (z == 0) ? W0 : (z == 1) ? W1 : W2;
    u16* dst = WT + (size_t)z * 1024 * 1024;
    const int tx = threadIdx.x & 31, ty = threadIdx.x >> 5;
    const int n0 = blockIdx.x * 32, k0 = blockIdx.y * 32;
    #pragma unroll
    for (int p = 0; p < 4; ++p)
        tile[ty + p * 8][tx] = f2b(W[(size_t)(k0 + ty + p * 8) * 1024 + n0 + tx]);
    __syncthreads();
    #pragma unroll
    for (int p = 0; p < 4; ++p)
        dst[(size_t)(n0 + ty + p * 8) * 1024 + k0 + tx] = tile[tx][ty + p * 8];
}

// ---------------------------------------------------------------------------
// LayerNorm: x fp32 [rows][1024] -> y bf16, one block per row
// ---------------------------------------------------------------------------
__global__ __launch_bounds__(256) void ln_bf16(
    const float* __restrict__ xin, const float* __restrict__ gam,
    const float* __restrict__ bet, u16* __restrict__ yout)
{
    __shared__ float red[8];
    const int row = blockIdx.x, tid = threadIdx.x;
    float4 v = ((const float4*)(xin + (size_t)row * 1024))[tid];
    float s = v.x + v.y + v.z + v.w;
    #pragma unroll
    for (int o = 32; o > 0; o >>= 1) s += __shfl_xor(s, o, 64);
    if ((tid & 63) == 0) red[tid >> 6] = s;
    __syncthreads();
    const float mu = (red[0] + red[1] + red[2] + red[3]) * (1.f / 1024.f);
    const float dx = v.x - mu, dy = v.y - mu, dz = v.z - mu, dw = v.w - mu;
    float sq = dx * dx + dy * dy + dz * dz + dw * dw;
    #pragma unroll
    for (int o = 32; o > 0; o >>= 1) sq += __shfl_xor(sq, o, 64);
    if ((tid & 63) == 0) red[4 + (tid >> 6)] = sq;
    __syncthreads();
    const float var = (red[4] + red[5] + red[6] + red[7]) * (1.f / 1024.f);
    const float inv = rsqrtf(var + 1e-5f);
    const float4 G = ((const float4*)gam)[tid];
    const float4 Bt = ((const float4*)bet)[tid];
    u16x4 o;
    o[0] = f2b(dx * inv * G.x + Bt.x);
    o[1] = f2b(dy * inv * G.y + Bt.y);
    o[2] = f2b(dz * inv * G.z + Bt.z);
    o[3] = f2b(dw * inv * G.w + Bt.w);
    ((u16x4*)(yout + (size_t)row * 1024))[tid] = o;
}

// ---------------------------------------------------------------------------
// GEMM: C[M][N] = A[M][K](bf16) @ BT[N][K]^T(bf16) + epilogue
// v4: T3/T4 pipeline — 3 LDS buffers, prefetch depth 2, counted
// s_waitcnt vmcnt(6) at consume (never 0 in steady state), raw s_barrier,
// ONE barrier per K-step. 128x64 tile, BK=64, 4 waves (2x2), 72KB LDS ->
// 2 blocks/CU for every N. global_load_lds w=16 with XOR swizzle via
// pre-swizzled global source. grid.x = M-blocks, grid.y = N-blocks.
// MODE 0: bias(3-way QKV select), out bf16
// MODE 1: bias + residual(fp32), out fp32
// MODE 2: bias + exact GELU, out bf16
// ---------------------------------------------------------------------------
template <int MODE, int BN>
__global__ __launch_bounds__(256) void gemm_bf16(
    const u16* __restrict__ A, const u16* __restrict__ BT,
    const float* __restrict__ b0, const float* __restrict__ b1,
    const float* __restrict__ b2, const float* __restrict__ resid,
    void* __restrict__ outp, int M, int N, int K)
{
    constexpr int NI = BN / 32;               // per-wave n-fragments (2 for BN=64)
    constexpr int AELEM = 128 * 64;
    constexpr int BELEM = BN * 64;
    __shared__ u16 Asm[3 * AELEM];
    __shared__ u16 Bsm[3 * BELEM];
    const int tid = threadIdx.x;
    const int lane = tid & 63, wid = tid >> 6;
    const int bm0 = blockIdx.x * 128, bn0 = blockIdx.y * BN;
    const int wm = wid >> 1, wn = wid & 1;
    const int g = lane >> 4, l16 = lane & 15;
    const int srow = lane >> 3;              // 0..7 within 8-row chunk
    const int sslot = (lane & 7) ^ srow;     // inverse-swizzled k-slot (16B units)

    f32x4 acc[4][NI] = {};

    const u16* aBase = A + (size_t)bm0 * K + sslot * 8;
    const u16* bBase = BT + (size_t)bn0 * K + sslot * 8;

    // per-wave loads per stage: 4 (A) + NI (B)  -> steady-state vmcnt = that
    auto stage = [&](int kt, int buf) {
        u16* adst = Asm + buf * AELEM;
        u16* bdst = Bsm + buf * BELEM;
        #pragma unroll
        for (int j = 0; j < 4; ++j) {
            const int inst = wid * 4 + j;          // 16 insts of 16 rows... (8 rows)
            const int row = inst * 8 + srow;       // 0..127
            __builtin_amdgcn_global_load_lds(AS1(aBase + (size_t)row * K + kt),
                                             AS3(adst + inst * 512), 16, 0, 0);
        }
        #pragma unroll
        for (int j = 0; j < NI; ++j) {
            const int inst = wid * NI + j;         // BN/8 insts
            const int row = inst * 8 + srow;       // 0..BN-1
            __builtin_amdgcn_global_load_lds(AS1(bBase + (size_t)row * K + kt),
                                             AS3(bdst + inst * 512), 16, 0, 0);
        }
    };

    const int nt = K / 64;
    stage(0, 0);
    stage(64, 1);        // nt >= 16 for all our shapes
    int cur = 0, pre = 2;

    for (int t = 0; t < nt; ++t) {
        // wait for tile t's loads: one newer stage (4+NI loads) may stay in flight
        if (t + 1 < nt) {
            if constexpr (NI == 2) asm volatile("s_waitcnt vmcnt(6)" ::: "memory");
            else                   asm volatile("s_waitcnt vmcnt(8)" ::: "memory");
        } else {
            asm volatile("s_waitcnt vmcnt(0)" ::: "memory");
        }
        __builtin_amdgcn_s_barrier();            // tile t visible to all waves
        __builtin_amdgcn_sched_barrier(0);

        const u16* asrc = Asm + cur * AELEM;
        const u16* bsrc = Bsm + cur * BELEM;
        bf16x8 af[2][4], bfr[2][NI];
        #pragma unroll
        for (int ks = 0; ks < 2; ++ks) {
            #pragma unroll
            for (int mi = 0; mi < 4; ++mi) {
                const int r = wm * 64 + mi * 16 + l16;
                const int slot = (g + 4 * ks) ^ (r & 7);   // swizzled read
                af[ks][mi] = *(const bf16x8*)(asrc + r * 64 + slot * 8);
            }
            #pragma unroll
            for (int ni = 0; ni < NI; ++ni) {
                const int r = wn * (BN / 2) + ni * 16 + l16;
                const int slot = (g + 4 * ks) ^ (r & 7);
                bfr[ks][ni] = *(const bf16x8*)(bsrc + r * 64 + slot * 8);
            }
        }
        // prefetch t+2 into the buffer read at t-1 (safe: its reads were
        // consumed before MFMA(t-1), which precedes this step's barrier)
        if (t + 2 < nt) stage((t + 2) * 64, pre);

        #pragma unroll
        for (int ks = 0; ks < 2; ++ks)
            #pragma unroll
            for (int mi = 0; mi < 4; ++mi)
                #pragma unroll
                for (int ni = 0; ni < NI; ++ni)
                    acc[mi][ni] = __builtin_amdgcn_mfma_f32_16x16x32_bf16(
                        af[ks][mi], bfr[ks][ni], acc[mi][ni], 0, 0, 0);

        pre = cur;
        cur = (cur == 2) ? 0 : cur + 1;
    }

    #pragma unroll
    for (int mi = 0; mi < 4; ++mi) {
        #pragma unroll
        for (int ni = 0; ni < NI; ++ni) {
            #pragma unroll
            for (int j = 0; j < 4; ++j) {
                const int m = bm0 + wm * 64 + mi * 16 + g * 4 + j;  // C/D: row=4g+j
                const int n = bn0 + wn * (BN / 2) + ni * 16 + l16;  // C/D: col=l16
                float v = acc[mi][ni][j];
                if constexpr (MODE == 0) {
                    const float bias = (n < 1024) ? b0[n]
                                      : (n < 2048) ? b1[n - 1024] : b2[n - 2048];
                    ((u16*)outp)[(size_t)m * N + n] = f2b(v + bias);
                } else if constexpr (MODE == 1) {
                    ((float*)outp)[(size_t)m * N + n] =
                        v + b0[n] + resid[(size_t)m * N + n];
                } else {
                    ((u16*)outp)[(size_t)m * N + n] = f2b(gelu_exact(v + b0[n]));
                }
            }
        }
    }
}

// ---------------------------------------------------------------------------
// Flash attention (causal): qkv bf16 [4096][3072] (q|k|v per row, head-major)
// Paired q-tiles {x, 15-x} -> uniform load; T14 async staging; V^T via
// in-register 4x4 transpose; same-(b,h) blocks grouped per XCD.
// Grid (8, 64), 4 waves x 16 q-rows.
// ---------------------------------------------------------------------------
__global__ __launch_bounds__(256) void attn_fwd(
    const u16* __restrict__ qkv, u16* __restrict__ outp)
{
    __shared__ u16 Ksm[64 * 72];        // K tile [kv][d], +8 pad
    __shared__ u16 Vsm[64 * 72];        // V^T tile [d][kv], +8 pad
    __shared__ u16 Psm[4][16 * 72];     // per-wave P [16 q][64 kv], +8 pad
    const int tid = threadIdx.x, lane = tid & 63, w = tid >> 6;
    const int lin = blockIdx.y * 8 + blockIdx.x;        // 0..511
    const int xq = (lin >> 3) & 7;                      // base q-pair index 0..7
    const int bh = (((lin >> 6) & 7) << 3) | (lin & 7); // 0..63
    const int b = bh >> 4, h = bh & 15;
    const int g = lane >> 4, l16 = lane & 15;
    const int skv = tid >> 4;            // 0..15 staging row group
    const int sd4 = (tid & 15) * 4;      // 0..60 staging d offset

    const u16* kvb = qkv + (size_t)(b * 1024) * 3072 + 1024 + h * 64; // K base

    u16x4 kreg[4], vreg[4];
    auto issue = [&](int kv0) {
        const u16* kb = kvb + (size_t)kv0 * 3072;
        #pragma unroll
        for (int i = 0; i < 4; ++i)
            kreg[i] = *(const u16x4*)(kb + (size_t)(skv + 16 * i) * 3072 + sd4);
        #pragma unroll
        for (int i = 0; i < 4; ++i)
            vreg[i] = *(const u16x4*)(kb + (size_t)(4 * skv + i) * 3072 + 1024 + sd4);
    };

    #pragma unroll
    for (int half = 0; half < 2; ++half) {
        const int qt = half ? (15 - xq) : xq;
        const int q0 = qt * 64;

        bf16x8 qf0, qf1;   // Q fragment: row=l16, k(d)=8g(+32)
        {
            const u16* qp = qkv + (size_t)(b * 1024 + q0 + w * 16 + l16) * 3072
                            + h * 64 + g * 8;
            qf0 = *(const bf16x8*)qp;
            qf1 = *(const bf16x8*)(qp + 32);
        }
        float m_run[4] = {-1e30f, -1e30f, -1e30f, -1e30f};
        float l_run[4] = {0.f, 0.f, 0.f, 0.f};
        f32x4 oacc[4] = {};

        issue(0);  // prologue loads for tile 0

        for (int kvt = 0; kvt <= qt; ++kvt) {
            const int kv0 = kvt * 64;
            __syncthreads();   // all waves done reading previous LDS tile
            #pragma unroll
            for (int i = 0; i < 4; ++i)
                *(u16x4*)(Ksm + (skv + 16 * i) * 72 + sd4) = kreg[i];
            #pragma unroll
            for (int j = 0; j < 4; ++j) {
                u16x4 t;
                t[0] = vreg[0][j]; t[1] = vreg[1][j];
                t[2] = vreg[2][j]; t[3] = vreg[3][j];
                *(u16x4*)(Vsm + (sd4 + j) * 72 + 4 * skv) = t;
            }
            __syncthreads();   // tile visible to all waves
            if (kvt < qt) issue(kv0 + 64);   // next tile loads fly under compute

            // S = Q K^T  (4 kv-column tiles of 16)
            f32x4 s[4];
            #pragma unroll
            for (int t = 0; t < 4; ++t) {
                const bf16x8 kf0 = *(const bf16x8*)(Ksm + (t * 16 + l16) * 72 + g * 8);
                const bf16x8 kf1 = *(const bf16x8*)(Ksm + (t * 16 + l16) * 72 + 32 + g * 8);
                f32x4 z = {};
                z = __builtin_amdgcn_mfma_f32_16x16x32_bf16(qf0, kf0, z, 0, 0, 0);
                z = __builtin_amdgcn_mfma_f32_16x16x32_bf16(qf1, kf1, z, 0, 0, 0);
                s[t] = z;
            }
            // scale + causal mask + row max
            float mx[4] = {-1e30f, -1e30f, -1e30f, -1e30f};
            #pragma unroll
            for (int t = 0; t < 4; ++t)
                #pragma unroll
                for (int j = 0; j < 4; ++j) {
                    const int qrow = q0 + w * 16 + g * 4 + j;
                    const int kvc = kv0 + t * 16 + l16;
                    float v = s[t][j] * 0.125f;
                    if (kvc > qrow) v = -1e30f;
                    s[t][j] = v;
                    mx[j] = fmaxf(mx[j], v);
                }
            #pragma unroll
            for (int o = 1; o < 16; o <<= 1)
                #pragma unroll
                for (int j = 0; j < 4; ++j)
                    mx[j] = fmaxf(mx[j], __shfl_xor(mx[j], o, 16));
            float alpha[4], rs[4];
            #pragma unroll
            for (int j = 0; j < 4; ++j) {
                const float mn = fmaxf(m_run[j], mx[j]);
                alpha[j] = __expf(m_run[j] - mn);
                m_run[j] = mn;
                rs[j] = 0.f;
            }
            #pragma unroll
            for (int t = 0; t < 4; ++t)
                #pragma unroll
                for (int j = 0; j < 4; ++j) {
                    const float p = __expf(s[t][j] - m_run[j]);
                    s[t][j] = p;
                    rs[j] += p;
                }
            #pragma unroll
            for (int o = 1; o < 16; o <<= 1)
                #pragma unroll
                for (int j = 0; j < 4; ++j)
                    rs[j] += __shfl_xor(rs[j], o, 16);
            #pragma unroll
            for (int j = 0; j < 4; ++j)
                l_run[j] = l_run[j] * alpha[j] + rs[j];
            #pragma unroll
            for (int dt = 0; dt < 4; ++dt)
                #pragma unroll
                for (int j = 0; j < 4; ++j)
                    oacc[dt][j] *= alpha[j];
            // P -> LDS (C-layout) -> A-fragment layout (per-wave buffer)
            #pragma unroll
            for (int t = 0; t < 4; ++t)
                #pragma unroll
                for (int j = 0; j < 4; ++j)
                    Psm[w][(g * 4 + j) * 72 + t * 16 + l16] = f2b(s[t][j]);
            const bf16x8 pf0 = *(const bf16x8*)(&Psm[w][l16 * 72 + g * 8]);
            const bf16x8 pf1 = *(const bf16x8*)(&Psm[w][l16 * 72 + 32 + g * 8]);
            // O += P V
            #pragma unroll
            for (int dt = 0; dt < 4; ++dt) {
                const bf16x8 vf0 = *(const bf16x8*)(Vsm + (dt * 16 + l16) * 72 + g * 8);
                const bf16x8 vf1 = *(const bf16x8*)(Vsm + (dt * 16 + l16) * 72 + 32 + g * 8);
                oacc[dt] = __builtin_amdgcn_mfma_f32_16x16x32_bf16(pf0, vf0, oacc[dt], 0, 0, 0);
                oacc[dt] = __builtin_amdgcn_mfma_f32_16x16x32_bf16(pf1, vf1, oacc[dt], 0, 0, 0);
            }
        }
        #pragma unroll
        for (int dt = 0; dt < 4; ++dt)
            #pragma unroll
            for (int j = 0; j < 4; ++j) {
                const int m = b * 1024 + q0 + w * 16 + g * 4 + j;
                const int col = h * 64 + dt * 16 + l16;
                outp[(size_t)m * 1024 + col] = f2b(oacc[dt][j] / l_run[j]);
            }
    }
}

// ---------------------------------------------------------------------------
extern "C" void kernel_launch(void* const* d_in, const int* in_sizes, int n_in,
                              void* d_out, int out_size, void* d_ws, size_t ws_size,
                              hipStream_t stream)
{
    const float* x   = (const float*)d_in[0];
    const float* Wq  = (const float*)d_in[1];
    const float* bq  = (const float*)d_in[2];
    const float* Wk  = (const float*)d_in[3];
    const float* bk  = (const float*)d_in[4];
    const float* Wv  = (const float*)d_in[5];
    const float* bv  = (const float*)d_in[6];
    const float* Wp  = (const float*)d_in[7];
    const float* bp  = (const float*)d_in[8];
    const float* W1  = (const float*)d_in[9];
    const float* b1  = (const float*)d_in[10];
    const float* W2  = (const float*)d_in[11];
    const float* b2  = (const float*)d_in[12];
    const float* g1  = (const float*)d_in[13];
    const float* be1 = (const float*)d_in[14];
    const float* g2  = (const float*)d_in[15];
    const float* be2 = (const float*)d_in[16];

    char* ws = (char*)d_ws;
    const size_t MB = 1024 * 1024;
    u16*   ln_buf = (u16*)(ws);              //  8 MB  [4096][1024] bf16
    u16*   qkv    = (u16*)(ws + 8 * MB);     // 24 MB  [4096][3072] bf16
    u16*   attn_o = (u16*)(ws + 32 * MB);    //  8 MB  [4096][1024] bf16
    float* x1     = (float*)(ws + 40 * MB);  // 16 MB  [4096][1024] f32
    u16*   hbuf   = (u16*)(ws + 56 * MB);    // 32 MB  [4096][4096] bf16
    u16*   wqkvT  = (u16*)(ws + 88 * MB);    //  6 MB  [3072][1024] bf16
    u16*   wpT    = (u16*)(ws + 94 * MB);    //  2 MB  [1024][1024] bf16
    u16*   w1T    = (u16*)(ws + 96 * MB);    //  8 MB  [4096][1024] bf16
    u16*   w2T    = (u16*)(ws + 104 * MB);   //  8 MB  [1024][4096] bf16

    transpose_w3<<<dim3(32, 32, 3), 256, 0, stream>>>(Wq, Wk, Wv, wqkvT);
    transpose_w<<<dim3(32, 32), 256, 0, stream>>>(Wp, wpT, 1024, 1024);
    transpose_w<<<dim3(128, 32), 256, 0, stream>>>(W1, w1T, 1024, 4096);
    transpose_w<<<dim3(32, 128), 256, 0, stream>>>(W2, w2T, 4096, 1024);

    ln_bf16<<<4096, 256, 0, stream>>>(x, g1, be1, ln_buf);
    gemm_bf16<0, 64><<<dim3(32, 48), 256, 0, stream>>>(
        ln_buf, wqkvT, bq, bk, bv, nullptr, qkv, 4096, 3072, 1024);
    attn_fwd<<<dim3(8, 64), 256, 0, stream>>>(qkv, attn_o);
    gemm_bf16<1, 64><<<dim3(32, 16), 256, 0, stream>>>(
        attn_o, wpT, bp, nullptr, nullptr, x, x1, 4096, 1024, 1024);
    ln_bf16<<<4096, 256, 0, stream>>>(x1, g2, be2, ln_buf);
    gemm_bf16<2, 64><<<dim3(32, 64), 256, 0, stream>>>(
        ln_buf, w1T, b1, nullptr, nullptr, nullptr, hbuf, 4096, 4096, 1024);
    gemm_bf16<1, 64><<<dim3(32, 16), 256, 0, stream>>>(
        hbuf, w2T, b2, nullptr, nullptr, x1, (float*)d_out, 4096, 1024, 4096);
}